// Round 7
// baseline (291.535 us; speedup 1.0000x reference)
//
#include <hip/hip_runtime.h>

static constexpr int NN = 50000;   // nodes
static constexpr int NE = 800000;  // edges
static constexpr int F  = 128;     // input features
static constexpr int H  = 64;      // hidden
static constexpr int C  = 40;      // classes

static constexpr int NB_BK = 8;          // node buckets (XCD-aligned)
static constexpr int NCH   = 32;         // edge chunks
static constexpr int ECH   = NE / NCH;   // 25000 edges per chunk
static constexpr int NBK   = NN / NB_BK; // 6250 nodes per bucket

// ---------------- CSR build: XCD-aligned counting sort ----------------------

__global__ __launch_bounds__(256) void k_hist(const int* __restrict__ ei,
                                              int* __restrict__ hist) {
  __shared__ int cnt[NBK];
  int i = blockIdx.x & 7;
  int j = blockIdx.x >> 3;
  for (int t = threadIdx.x; t < NBK; t += 256) cnt[t] = 0;
  __syncthreads();
  int lo = i * NBK;
  const int* dst = ei + NE + j * ECH;
  for (int base = threadIdx.x * 4; base < ECH; base += 256 * 4) {
    int4 d4 = *reinterpret_cast<const int4*>(dst + base);
    if ((unsigned)(d4.x - lo) < (unsigned)NBK) atomicAdd(&cnt[d4.x - lo], 1);
    if ((unsigned)(d4.y - lo) < (unsigned)NBK) atomicAdd(&cnt[d4.y - lo], 1);
    if ((unsigned)(d4.z - lo) < (unsigned)NBK) atomicAdd(&cnt[d4.z - lo], 1);
    if ((unsigned)(d4.w - lo) < (unsigned)NBK) atomicAdd(&cnt[d4.w - lo], 1);
  }
  __syncthreads();
  int* hrow = hist + (size_t)j * NN + lo;
  for (int t = threadIdx.x; t < NBK; t += 256) hrow[t] = cnt[t];
}

__global__ __launch_bounds__(256) void k_scan(int* __restrict__ hist,
                                              int* __restrict__ deg,
                                              int* __restrict__ start,
                                              int* __restrict__ counter) {
  int lane = threadIdx.x & 63;
  int wid  = (blockIdx.x * blockDim.x + threadIdx.x) >> 6;
  int nw   = (gridDim.x * blockDim.x) >> 6;
  int nchunks = (NN + 63) >> 6;
  for (int c = wid; c < nchunks; c += nw) {
    int n = (c << 6) + lane;
    int d = 0;
    if (n < NN) {
      int run = 0;
#pragma unroll
      for (int j = 0; j < NCH; ++j) {
        int v = hist[(size_t)j * NN + n];
        hist[(size_t)j * NN + n] = run;
        run += v;
      }
      d = run;
    }
    int inc = d;
#pragma unroll
    for (int off = 1; off < 64; off <<= 1) {
      int t = __shfl_up(inc, off, 64);
      if (lane >= off) inc += t;
    }
    int total = __shfl(inc, 63, 64);
    int base = 0;
    if (lane == 63) base = atomicAdd(counter, total);
    base = __shfl(base, 63, 64);
    if (n < NN) {
      deg[n]   = d;
      start[n] = base + inc - d;
    }
  }
}

__global__ __launch_bounds__(256) void k_fill2(const int* __restrict__ ei,
                                               const int* __restrict__ hist,
                                               const int* __restrict__ start,
                                               int* __restrict__ csr_src) {
  __shared__ int fill[NBK];
  int i = blockIdx.x & 7;
  int j = blockIdx.x >> 3;
  int lo = i * NBK;
  const int* hrow = hist + (size_t)j * NN + lo;
  for (int t = threadIdx.x; t < NBK; t += 256) fill[t] = start[lo + t] + hrow[t];
  __syncthreads();
  const int* srcp = ei + j * ECH;
  const int* dstp = ei + NE + j * ECH;
  for (int base = threadIdx.x * 4; base < ECH; base += 256 * 4) {
    int4 s4 = *reinterpret_cast<const int4*>(srcp + base);
    int4 d4 = *reinterpret_cast<const int4*>(dstp + base);
    if ((unsigned)(d4.x - lo) < (unsigned)NBK) { int p = atomicAdd(&fill[d4.x - lo], 1); csr_src[p] = s4.x; }
    if ((unsigned)(d4.y - lo) < (unsigned)NBK) { int p = atomicAdd(&fill[d4.y - lo], 1); csr_src[p] = s4.y; }
    if ((unsigned)(d4.z - lo) < (unsigned)NBK) { int p = atomicAdd(&fill[d4.z - lo], 1); csr_src[p] = s4.z; }
    if ((unsigned)(d4.w - lo) < (unsigned)NBK) { int p = atomicAdd(&fill[d4.w - lo], 1); csr_src[p] = s4.w; }
  }
}

// ---------------- dense MM: 128-node tile, 2 nodes/lane, K-chunked LDS ------
// LDS chunk [k][node] (pad 130): staging writes ~2-way (free), compute
// ds_read_b64 aggregate-conflict-free. 4 waves split (mat x j-seg); weights
// via wave-uniform s_load -- 128 cyc FMA per 128B load (1 B/cyc, pipelined).

template <int K1, int K2, int J, int JT, int NMAT, bool BIAS, bool RELU>
__global__ __launch_bounds__(256) void k_mm(const float* __restrict__ X1,
                                            const float* __restrict__ X2,
                                            const float* __restrict__ W0,
                                            const float* __restrict__ W1,
                                            const float* __restrict__ bias,
                                            float* __restrict__ Y0,
                                            float* __restrict__ Y1) {
  constexpr int K   = K1 + K2;
  constexpr int MB  = 128;   // nodes per block
  constexpr int KC  = 32;    // k-chunk
  constexpr int LDW = 130;   // padded row (dwords)
  constexpr int NKC = K / KC;
  __shared__ float xs[KC * LDW];

  int n0   = blockIdx.x * MB;
  int lane = threadIdx.x & 63;
  int wv   = __builtin_amdgcn_readfirstlane(threadIdx.x >> 6);
  int mat  = (NMAT == 2) ? (wv >> 1) : 0;
  int jseg = (NMAT == 2) ? (wv & 1) : wv;
  int jb   = jseg * JT;
  const float* W = (NMAT == 2 && mat) ? W1 : W0;
  float*       Y = (NMAT == 2 && mat) ? Y1 : Y0;

  float accA[JT], accB[JT];
#pragma unroll
  for (int j = 0; j < JT; ++j) {
    float b = BIAS ? bias[jb + j] : 0.f;
    accA[j] = b; accB[j] = b;
  }

  for (int c = 0; c < NKC; ++c) {
    // chunk source (uniform): first K1 k's from X1, rest from X2
    const float* Xs_; int rs, koff;
    if (c * KC < K1) { Xs_ = X1; rs = K1; koff = c * KC; }
    else             { Xs_ = X2; rs = K2; koff = c * KC - K1; }

    if (c) __syncthreads();
    for (int i = threadIdx.x; i < MB * (KC / 4); i += 256) {
      int n = i >> 3;        // KC/4 == 8
      int q = i & 7;
      int nn = n0 + n; if (nn > NN - 1) nn = NN - 1;
      float4 v = *reinterpret_cast<const float4*>(Xs_ + (size_t)nn * rs + koff + q * 4);
      xs[(q * 4 + 0) * LDW + n] = v.x;
      xs[(q * 4 + 1) * LDW + n] = v.y;
      xs[(q * 4 + 2) * LDW + n] = v.z;
      xs[(q * 4 + 3) * LDW + n] = v.w;
    }
    __syncthreads();

#pragma unroll
    for (int k = 0; k < KC; ++k) {
      float2 xv = *reinterpret_cast<const float2*>(&xs[k * LDW + 2 * lane]);
      const float* wr = W + (size_t)(c * KC + k) * J + jb;
#pragma unroll
      for (int j = 0; j < JT; ++j) {
        float wj = wr[j];
        accA[j] = fmaf(xv.x, wj, accA[j]);
        accB[j] = fmaf(xv.y, wj, accB[j]);
      }
    }
  }

  int na = n0 + 2 * lane;
  if (na < NN) {
    float* yp = Y + (size_t)na * J + jb;
#pragma unroll
    for (int j = 0; j < JT; j += 4) {
      float4 t = {accA[j], accA[j + 1], accA[j + 2], accA[j + 3]};
      if (RELU) {
        t.x = fmaxf(t.x, 0.f); t.y = fmaxf(t.y, 0.f);
        t.z = fmaxf(t.z, 0.f); t.w = fmaxf(t.w, 0.f);
      }
      *reinterpret_cast<float4*>(yp + j) = t;
    }
  }
  if (na + 1 < NN) {
    float* yp = Y + (size_t)(na + 1) * J + jb;
#pragma unroll
    for (int j = 0; j < JT; j += 4) {
      float4 t = {accB[j], accB[j + 1], accB[j + 2], accB[j + 3]};
      if (RELU) {
        t.x = fmaxf(t.x, 0.f); t.y = fmaxf(t.y, 0.f);
        t.z = fmaxf(t.z, 0.f); t.w = fmaxf(t.w, 0.f);
      }
      *reinterpret_cast<float4*>(yp + j) = t;
    }
  }
}

// ---------------- aggregation: scalar CSR fetch + 8-deep gather MLP ---------

template <int JC, bool RELU>
__global__ __launch_bounds__(256) void k_agg(const float* __restrict__ p,
                                             const float* __restrict__ q,
                                             const float* __restrict__ bl,
                                             const int* __restrict__ deg,
                                             const int* __restrict__ start,
                                             const int* __restrict__ csr_src,
                                             float* __restrict__ outp) {
  int lane = threadIdx.x & 63;
  int wid  = (blockIdx.x * blockDim.x + threadIdx.x) >> 6;
  int nw   = (gridDim.x * blockDim.x) >> 6;
  bool jl = lane < JC;
  int lidx = jl ? lane : 0;
  for (int node = wid; node < NN; node += nw) {
    int d  = __builtin_amdgcn_readfirstlane(deg[node]);
    int st = __builtin_amdgcn_readfirstlane(start[node]);
    float a0 = 0.f, a1 = 0.f, a2 = 0.f, a3 = 0.f;
    float a4 = 0.f, a5 = 0.f, a6 = 0.f, a7 = 0.f;
    int t = 0;
    for (; t + 8 <= d; t += 8) {
      int s0 = __builtin_amdgcn_readfirstlane(csr_src[st + t + 0]);
      int s1 = __builtin_amdgcn_readfirstlane(csr_src[st + t + 1]);
      int s2 = __builtin_amdgcn_readfirstlane(csr_src[st + t + 2]);
      int s3 = __builtin_amdgcn_readfirstlane(csr_src[st + t + 3]);
      int s4 = __builtin_amdgcn_readfirstlane(csr_src[st + t + 4]);
      int s5 = __builtin_amdgcn_readfirstlane(csr_src[st + t + 5]);
      int s6 = __builtin_amdgcn_readfirstlane(csr_src[st + t + 6]);
      int s7 = __builtin_amdgcn_readfirstlane(csr_src[st + t + 7]);
      a0 += p[(size_t)s0 * JC + lidx];
      a1 += p[(size_t)s1 * JC + lidx];
      a2 += p[(size_t)s2 * JC + lidx];
      a3 += p[(size_t)s3 * JC + lidx];
      a4 += p[(size_t)s4 * JC + lidx];
      a5 += p[(size_t)s5 * JC + lidx];
      a6 += p[(size_t)s6 * JC + lidx];
      a7 += p[(size_t)s7 * JC + lidx];
    }
    if (t + 4 <= d) {
      int s0 = __builtin_amdgcn_readfirstlane(csr_src[st + t + 0]);
      int s1 = __builtin_amdgcn_readfirstlane(csr_src[st + t + 1]);
      int s2 = __builtin_amdgcn_readfirstlane(csr_src[st + t + 2]);
      int s3 = __builtin_amdgcn_readfirstlane(csr_src[st + t + 3]);
      a0 += p[(size_t)s0 * JC + lidx];
      a1 += p[(size_t)s1 * JC + lidx];
      a2 += p[(size_t)s2 * JC + lidx];
      a3 += p[(size_t)s3 * JC + lidx];
      t += 4;
    }
    for (; t < d; ++t) {
      int s = __builtin_amdgcn_readfirstlane(csr_src[st + t]);
      a0 += p[(size_t)s * JC + lidx];
    }
    float acc = ((a0 + a1) + (a2 + a3)) + ((a4 + a5) + (a6 + a7));
    float mean = acc / fmaxf((float)d, 1.0f);
    float v = 0.f;
    if (jl) v = mean + bl[lidx] + q[(size_t)node * JC + lidx];
    float ss = v * v;
#pragma unroll
    for (int off = 32; off > 0; off >>= 1) ss += __shfl_xor(ss, off, 64);
    v = v / fmaxf(sqrtf(ss), 1e-12f);
    if (RELU) v = fmaxf(v, 0.f);
    if (jl) outp[(size_t)node * JC + lidx] = v;
  }
}

// ---------------- launch ----------------------------------------------------

static inline size_t align256(size_t x) { return (x + 255) & ~(size_t)255; }

extern "C" void kernel_launch(void* const* d_in, const int* in_sizes, int n_in,
                              void* d_out, int out_size, void* d_ws, size_t ws_size,
                              hipStream_t stream) {
  const float* x    = (const float*)d_in[0];
  const int*   ei   = (const int*)d_in[1];
  const float* Wl1  = (const float*)d_in[2];
  const float* bl1  = (const float*)d_in[3];
  const float* Wr1  = (const float*)d_in[4];
  const float* Wlin = (const float*)d_in[5];
  const float* blin = (const float*)d_in[6];
  const float* Wl2  = (const float*)d_in[7];
  const float* bl2  = (const float*)d_in[8];
  const float* Wr2  = (const float*)d_in[9];
  float* out = (float*)d_out;

  char* w = (char*)d_ws;
  size_t off = 0;
  int* deg     = (int*)(w + off); off += align256((size_t)NN * 4);
  int* start   = (int*)(w + off); off += align256((size_t)NN * 4);
  int* counter = (int*)(w + off); off += 256;
  int* csr_src = (int*)(w + off); off += align256((size_t)NE * 4);
  float* bufP  = (float*)(w + off); off += align256((size_t)2 * NN * H * 4);  // 25.6 MB
  float* hidden= (float*)(w + off); off += align256((size_t)NN * H * 4);      // 12.8 MB
  float* bufQ  = (float*)(w + off); off += align256((size_t)2 * NN * C * 4);  // 16 MB

  // liveness overlays:
  int*   hist = (int*)bufP;               // CSR build only (dead before gemm1)
  float* p1   = bufP;                     // gemm1 -> agg1
  float* q1   = bufP + (size_t)NN * H;    // gemm1 -> agg1
  float* h    = bufP;                     // lin1 -> gemm2 (p1/q1 dead)
  float* p2   = bufQ;                     // gemm2 -> agg2
  float* q2   = bufQ + (size_t)NN * C;

  hipMemsetAsync(counter, 0, 4, stream);

  const int T = 256;
  const int NT128 = (NN + 127) / 128;  // 391

  // CSR build: counting sort, no device atomics per edge
  k_hist <<<NB_BK * NCH, T, 0, stream>>>(ei, hist);
  k_scan <<<196, T, 0, stream>>>(hist, deg, start, counter);
  k_fill2<<<NB_BK * NCH, T, 0, stream>>>(ei, hist, start, csr_src);

  // p1 = x@Wl1, q1 = x@Wr1
  k_mm<F, 0, H, 32, 2, false, false><<<NT128, T, 0, stream>>>(
      x, nullptr, Wl1, Wr1, nullptr, p1, q1);

  // hidden = relu(l2norm(mean_agg(p1) + bl1 + q1))
  k_agg<H, true><<<2048, T, 0, stream>>>(p1, q1, bl1, deg, start, csr_src, hidden);

  // h = relu([x, hidden] @ Wlin + blin)   (p1/q1 dead -> h overlays bufP)
  k_mm<F, H, H, 16, 1, true, true><<<NT128, T, 0, stream>>>(
      x, hidden, Wlin, nullptr, blin, h, nullptr);

  // p2 = h@Wl2, q2 = h@Wr2
  k_mm<H, 0, C, 20, 2, false, false><<<NT128, T, 0, stream>>>(
      h, nullptr, Wl2, Wr2, nullptr, p2, q2);

  // out = l2norm(mean_agg(p2) + bl2 + q2)
  k_agg<C, false><<<2048, T, 0, stream>>>(p2, q2, bl2, deg, start, csr_src, out);
}

// Round 8
// 232.349 us; speedup vs baseline: 1.2547x; 1.2547x over previous
//
#include <hip/hip_runtime.h>

static constexpr int NN = 50000;   // nodes
static constexpr int NE = 800000;  // edges
static constexpr int F  = 128;     // input features
static constexpr int H  = 64;      // hidden
static constexpr int C  = 40;      // classes

static constexpr int NB_BK = 8;          // node buckets (XCD-aligned)
static constexpr int NCH   = 32;         // edge chunks
static constexpr int ECH   = NE / NCH;   // 25000 edges per chunk
static constexpr int NBK   = NN / NB_BK; // 6250 nodes per bucket

typedef __attribute__((ext_vector_type(8))) short bf16x8;
typedef __attribute__((ext_vector_type(4))) float f32x4;

__device__ inline unsigned short f2bf(float f) {
  unsigned int u = __builtin_bit_cast(unsigned int, f);
  u = (u + 0x7fff + ((u >> 16) & 1)) >> 16;  // RNE
  return (unsigned short)u;
}

// ---------------- CSR build: XCD-aligned counting sort ----------------------

__global__ __launch_bounds__(256) void k_hist(const int* __restrict__ ei,
                                              int* __restrict__ hist) {
  __shared__ int cnt[NBK];
  int i = blockIdx.x & 7;
  int j = blockIdx.x >> 3;
  for (int t = threadIdx.x; t < NBK; t += 256) cnt[t] = 0;
  __syncthreads();
  int lo = i * NBK;
  const int* dst = ei + NE + j * ECH;
  for (int base = threadIdx.x * 4; base < ECH; base += 256 * 4) {
    int4 d4 = *reinterpret_cast<const int4*>(dst + base);
    if ((unsigned)(d4.x - lo) < (unsigned)NBK) atomicAdd(&cnt[d4.x - lo], 1);
    if ((unsigned)(d4.y - lo) < (unsigned)NBK) atomicAdd(&cnt[d4.y - lo], 1);
    if ((unsigned)(d4.z - lo) < (unsigned)NBK) atomicAdd(&cnt[d4.z - lo], 1);
    if ((unsigned)(d4.w - lo) < (unsigned)NBK) atomicAdd(&cnt[d4.w - lo], 1);
  }
  __syncthreads();
  int* hrow = hist + (size_t)j * NN + lo;
  for (int t = threadIdx.x; t < NBK; t += 256) hrow[t] = cnt[t];
}

__global__ __launch_bounds__(256) void k_scan(int* __restrict__ hist,
                                              int* __restrict__ deg,
                                              int* __restrict__ start,
                                              int* __restrict__ counter) {
  int lane = threadIdx.x & 63;
  int wid  = (blockIdx.x * blockDim.x + threadIdx.x) >> 6;
  int nw   = (gridDim.x * blockDim.x) >> 6;
  int nchunks = (NN + 63) >> 6;
  for (int c = wid; c < nchunks; c += nw) {
    int n = (c << 6) + lane;
    int d = 0;
    if (n < NN) {
      int run = 0;
#pragma unroll
      for (int j = 0; j < NCH; ++j) {
        int v = hist[(size_t)j * NN + n];
        hist[(size_t)j * NN + n] = run;
        run += v;
      }
      d = run;
    }
    int inc = d;
#pragma unroll
    for (int off = 1; off < 64; off <<= 1) {
      int t = __shfl_up(inc, off, 64);
      if (lane >= off) inc += t;
    }
    int total = __shfl(inc, 63, 64);
    int base = 0;
    if (lane == 63) base = atomicAdd(counter, total);
    base = __shfl(base, 63, 64);
    if (n < NN) {
      deg[n]   = d;
      start[n] = base + inc - d;
    }
  }
}

__global__ __launch_bounds__(256) void k_fill2(const int* __restrict__ ei,
                                               const int* __restrict__ hist,
                                               const int* __restrict__ start,
                                               int* __restrict__ csr_src) {
  __shared__ int fill[NBK];
  int i = blockIdx.x & 7;
  int j = blockIdx.x >> 3;
  int lo = i * NBK;
  const int* hrow = hist + (size_t)j * NN + lo;
  for (int t = threadIdx.x; t < NBK; t += 256) fill[t] = start[lo + t] + hrow[t];
  __syncthreads();
  const int* srcp = ei + j * ECH;
  const int* dstp = ei + NE + j * ECH;
  for (int base = threadIdx.x * 4; base < ECH; base += 256 * 4) {
    int4 s4 = *reinterpret_cast<const int4*>(srcp + base);
    int4 d4 = *reinterpret_cast<const int4*>(dstp + base);
    if ((unsigned)(d4.x - lo) < (unsigned)NBK) { int p = atomicAdd(&fill[d4.x - lo], 1); csr_src[p] = s4.x; }
    if ((unsigned)(d4.y - lo) < (unsigned)NBK) { int p = atomicAdd(&fill[d4.y - lo], 1); csr_src[p] = s4.y; }
    if ((unsigned)(d4.z - lo) < (unsigned)NBK) { int p = atomicAdd(&fill[d4.z - lo], 1); csr_src[p] = s4.z; }
    if ((unsigned)(d4.w - lo) < (unsigned)NBK) { int p = atomicAdd(&fill[d4.w - lo], 1); csr_src[p] = s4.w; }
  }
}

// ---------------- x -> bf16 -------------------------------------------------

__global__ __launch_bounds__(256) void k_cvt(const float* __restrict__ x,
                                             unsigned short* __restrict__ xb) {
  int stride = gridDim.x * blockDim.x;
  for (int i = blockIdx.x * blockDim.x + threadIdx.x; i < NN * F / 4; i += stride) {
    float4 v = reinterpret_cast<const float4*>(x)[i];
    ushort4 o = {f2bf(v.x), f2bf(v.y), f2bf(v.z), f2bf(v.w)};
    reinterpret_cast<ushort4*>(xb)[i] = o;
  }
}

// ---------------- weight pack: fragment-ordered bf16 ------------------------
// Wf[s][nt][lane][j] = bf16(W[s*32 + (lane>>4)*8 + j][nt*16 + (lane&15)])
// -> each lane's B-fragment for (kstep s, ntile nt) is one contiguous 16B.

__device__ inline void packW(const float* __restrict__ W, int J, int NT,
                             unsigned short* __restrict__ Wf, int idx) {
  int j  = idx & 7;
  int l  = (idx >> 3) & 63;
  int nt = (idx >> 9) % NT;
  int s  = idx / (512 * NT);
  int k  = s * 32 + (l >> 4) * 8 + j;
  int n  = nt * 16 + (l & 15);
  float v = (n < J) ? W[k * J + n] : 0.f;
  Wf[idx] = f2bf(v);
}

__global__ __launch_bounds__(256) void k_prep(const float* __restrict__ Wl1,
                                              const float* __restrict__ Wr1,
                                              const float* __restrict__ Wlin,
                                              const float* __restrict__ Wl2,
                                              const float* __restrict__ Wr2,
                                              unsigned short* __restrict__ Wf1l,
                                              unsigned short* __restrict__ Wf1r,
                                              unsigned short* __restrict__ Wflin,
                                              unsigned short* __restrict__ Wf2l,
                                              unsigned short* __restrict__ Wf2r) {
  int id0 = blockIdx.x * blockDim.x + threadIdx.x;
  int ns  = gridDim.x * blockDim.x;
  for (int i = id0; i < 4 * 4 * 512; i += ns) packW(Wl1, 64, 4, Wf1l, i);
  for (int i = id0; i < 4 * 4 * 512; i += ns) packW(Wr1, 64, 4, Wf1r, i);
  for (int i = id0; i < 6 * 4 * 512; i += ns) packW(Wlin, 64, 4, Wflin, i);
  for (int i = id0; i < 2 * 3 * 512; i += ns) packW(Wl2, 40, 3, Wf2l, i);
  for (int i = id0; i < 2 * 3 * 512; i += ns) packW(Wr2, 40, 3, Wf2r, i);
}

// ---------------- dense GEMM via MFMA bf16 ----------------------------------
// Block = 64-node tile, wave = 16 rows. A-frag: A[m=lane&15][k=(lane>>4)*8+j]
// (16B global load / lane). B-frag from pre-packed Wf (16B load / lane).
// D: row=(lane>>4)*4+reg, col=lane&15 (m89-verified mapping).

template <int K1, int K2, int JOUT, int NT, int NMAT, bool BIAS, bool RELU, bool OUTBF>
__global__ __launch_bounds__(256) void k_mf(const unsigned short* __restrict__ A1,
                                            const unsigned short* __restrict__ A2,
                                            const unsigned short* __restrict__ Wf0,
                                            const unsigned short* __restrict__ Wf1,
                                            const float* __restrict__ bias,
                                            void* __restrict__ Y0v,
                                            void* __restrict__ Y1v) {
  constexpr int K   = K1 + K2;
  constexpr int NKS = K / 32;
  int lane = threadIdx.x & 63;
  int w    = __builtin_amdgcn_readfirstlane(threadIdx.x >> 6);
  int m    = lane & 15;
  int kg   = lane >> 4;
  int n0   = blockIdx.x * 64;
  int row  = n0 + w * 16 + m;
  int rowc = row < NN ? row : NN - 1;

  f32x4 acc[NMAT][NT];
#pragma unroll
  for (int mt = 0; mt < NMAT; ++mt)
#pragma unroll
    for (int nt = 0; nt < NT; ++nt) acc[mt][nt] = {0.f, 0.f, 0.f, 0.f};

#pragma unroll
  for (int s = 0; s < NKS; ++s) {
    const unsigned short* Ab; int rs, koff;
    if (s * 32 < K1) { Ab = A1; rs = K1; koff = s * 32; }
    else             { Ab = A2; rs = K2; koff = s * 32 - K1; }
    bf16x8 a = *reinterpret_cast<const bf16x8*>(Ab + (size_t)rowc * rs + koff + kg * 8);
#pragma unroll
    for (int mt = 0; mt < NMAT; ++mt) {
      const unsigned short* Wf = (NMAT == 2 && mt) ? Wf1 : Wf0;
#pragma unroll
      for (int nt = 0; nt < NT; ++nt) {
        bf16x8 b = *reinterpret_cast<const bf16x8*>(Wf + (size_t)((s * NT + nt) * 64 + lane) * 8);
        acc[mt][nt] = __builtin_amdgcn_mfma_f32_16x16x32_bf16(a, b, acc[mt][nt], 0, 0, 0);
      }
    }
  }

#pragma unroll
  for (int mt = 0; mt < NMAT; ++mt) {
    void* Yv = (NMAT == 2 && mt) ? Y1v : Y0v;
#pragma unroll
    for (int nt = 0; nt < NT; ++nt) {
      int gc = nt * 16 + m;
      bool cv = gc < JOUT;
      float bb = (BIAS && cv) ? bias[gc] : 0.f;
#pragma unroll
      for (int r = 0; r < 4; ++r) {
        int grow = n0 + w * 16 + kg * 4 + r;
        if (grow < NN && cv) {
          float v = acc[mt][nt][r] + bb;
          if (RELU) v = fmaxf(v, 0.f);
          if (OUTBF) ((unsigned short*)Yv)[(size_t)grow * JOUT + gc] = f2bf(v);
          else       ((float*)Yv)[(size_t)grow * JOUT + gc] = v;
        }
      }
    }
  }
}

// ---------------- aggregation: scalar CSR fetch + 8-deep gather MLP ---------

template <int JC, bool RELU, bool OUTBF>
__global__ __launch_bounds__(256) void k_agg(const float* __restrict__ p,
                                             const float* __restrict__ q,
                                             const float* __restrict__ bl,
                                             const int* __restrict__ deg,
                                             const int* __restrict__ start,
                                             const int* __restrict__ csr_src,
                                             void* __restrict__ outp) {
  int lane = threadIdx.x & 63;
  int wid  = (blockIdx.x * blockDim.x + threadIdx.x) >> 6;
  int nw   = (gridDim.x * blockDim.x) >> 6;
  bool jl = lane < JC;
  int lidx = jl ? lane : 0;
  for (int node = wid; node < NN; node += nw) {
    int d  = __builtin_amdgcn_readfirstlane(deg[node]);
    int st = __builtin_amdgcn_readfirstlane(start[node]);
    float a0 = 0.f, a1 = 0.f, a2 = 0.f, a3 = 0.f;
    float a4 = 0.f, a5 = 0.f, a6 = 0.f, a7 = 0.f;
    int t = 0;
    for (; t + 8 <= d; t += 8) {
      int s0 = __builtin_amdgcn_readfirstlane(csr_src[st + t + 0]);
      int s1 = __builtin_amdgcn_readfirstlane(csr_src[st + t + 1]);
      int s2 = __builtin_amdgcn_readfirstlane(csr_src[st + t + 2]);
      int s3 = __builtin_amdgcn_readfirstlane(csr_src[st + t + 3]);
      int s4 = __builtin_amdgcn_readfirstlane(csr_src[st + t + 4]);
      int s5 = __builtin_amdgcn_readfirstlane(csr_src[st + t + 5]);
      int s6 = __builtin_amdgcn_readfirstlane(csr_src[st + t + 6]);
      int s7 = __builtin_amdgcn_readfirstlane(csr_src[st + t + 7]);
      a0 += p[(size_t)s0 * JC + lidx];
      a1 += p[(size_t)s1 * JC + lidx];
      a2 += p[(size_t)s2 * JC + lidx];
      a3 += p[(size_t)s3 * JC + lidx];
      a4 += p[(size_t)s4 * JC + lidx];
      a5 += p[(size_t)s5 * JC + lidx];
      a6 += p[(size_t)s6 * JC + lidx];
      a7 += p[(size_t)s7 * JC + lidx];
    }
    if (t + 4 <= d) {
      int s0 = __builtin_amdgcn_readfirstlane(csr_src[st + t + 0]);
      int s1 = __builtin_amdgcn_readfirstlane(csr_src[st + t + 1]);
      int s2 = __builtin_amdgcn_readfirstlane(csr_src[st + t + 2]);
      int s3 = __builtin_amdgcn_readfirstlane(csr_src[st + t + 3]);
      a0 += p[(size_t)s0 * JC + lidx];
      a1 += p[(size_t)s1 * JC + lidx];
      a2 += p[(size_t)s2 * JC + lidx];
      a3 += p[(size_t)s3 * JC + lidx];
      t += 4;
    }
    for (; t < d; ++t) {
      int s = __builtin_amdgcn_readfirstlane(csr_src[st + t]);
      a0 += p[(size_t)s * JC + lidx];
    }
    float acc = ((a0 + a1) + (a2 + a3)) + ((a4 + a5) + (a6 + a7));
    float mean = acc / fmaxf((float)d, 1.0f);
    float v = 0.f;
    if (jl) v = mean + bl[lidx] + q[(size_t)node * JC + lidx];
    float ss = v * v;
#pragma unroll
    for (int off = 32; off > 0; off >>= 1) ss += __shfl_xor(ss, off, 64);
    v = v / fmaxf(sqrtf(ss), 1e-12f);
    if (RELU) v = fmaxf(v, 0.f);
    if (jl) {
      if (OUTBF) ((unsigned short*)outp)[(size_t)node * JC + lidx] = f2bf(v);
      else       ((float*)outp)[(size_t)node * JC + lidx] = v;
    }
  }
}

// ---------------- launch ----------------------------------------------------

static inline size_t align256(size_t x) { return (x + 255) & ~(size_t)255; }

extern "C" void kernel_launch(void* const* d_in, const int* in_sizes, int n_in,
                              void* d_out, int out_size, void* d_ws, size_t ws_size,
                              hipStream_t stream) {
  const float* x    = (const float*)d_in[0];
  const int*   ei   = (const int*)d_in[1];
  const float* Wl1  = (const float*)d_in[2];
  const float* bl1  = (const float*)d_in[3];
  const float* Wr1  = (const float*)d_in[4];
  const float* Wlin = (const float*)d_in[5];
  const float* blin = (const float*)d_in[6];
  const float* Wl2  = (const float*)d_in[7];
  const float* bl2  = (const float*)d_in[8];
  const float* Wr2  = (const float*)d_in[9];
  float* out = (float*)d_out;

  char* w = (char*)d_ws;
  size_t off = 0;
  int* deg     = (int*)(w + off); off += align256((size_t)NN * 4);
  int* start   = (int*)(w + off); off += align256((size_t)NN * 4);
  int* counter = (int*)(w + off); off += 256;
  int* csr_src = (int*)(w + off); off += align256((size_t)NE * 4);
  int* hist    = (int*)(w + off); off += align256((size_t)NCH * NN * 4);        // 6.4 MB
  unsigned short* xb      = (unsigned short*)(w + off); off += align256((size_t)NN * F * 2);  // 12.8 MB
  unsigned short* hiddenb = (unsigned short*)(w + off); off += align256((size_t)NN * H * 2);  // 6.4 MB
  unsigned short* hb      = (unsigned short*)(w + off); off += align256((size_t)NN * H * 2);  // 6.4 MB
  float* p1 = (float*)(w + off); off += align256((size_t)NN * H * 4);  // 12.8 MB
  float* q1 = (float*)(w + off); off += align256((size_t)NN * H * 4);  // 12.8 MB
  float* p2 = (float*)(w + off); off += align256((size_t)NN * C * 4);  // 8 MB
  float* q2 = (float*)(w + off); off += align256((size_t)NN * C * 4);  // 8 MB
  unsigned short* Wf1l  = (unsigned short*)(w + off); off += align256(4 * 4 * 512 * 2);
  unsigned short* Wf1r  = (unsigned short*)(w + off); off += align256(4 * 4 * 512 * 2);
  unsigned short* Wflin = (unsigned short*)(w + off); off += align256(6 * 4 * 512 * 2);
  unsigned short* Wf2l  = (unsigned short*)(w + off); off += align256(2 * 3 * 512 * 2);
  unsigned short* Wf2r  = (unsigned short*)(w + off); off += align256(2 * 3 * 512 * 2);

  hipMemsetAsync(counter, 0, 4, stream);

  const int T = 256;
  const int NT64 = (NN + 63) / 64;  // 782

  // CSR build: counting sort, no device atomics per edge
  k_hist <<<NB_BK * NCH, T, 0, stream>>>(ei, hist);
  k_scan <<<196, T, 0, stream>>>(hist, deg, start, counter);
  k_fill2<<<NB_BK * NCH, T, 0, stream>>>(ei, hist, start, csr_src);

  // bf16 conversions / weight fragment packing
  k_cvt <<<782, T, 0, stream>>>(x, xb);
  k_prep<<<48, T, 0, stream>>>(Wl1, Wr1, Wlin, Wl2, Wr2, Wf1l, Wf1r, Wflin, Wf2l, Wf2r);

  // p1 = x@Wl1, q1 = x@Wr1  (MFMA)
  k_mf<F, 0, H, 4, 2, false, false, false><<<NT64, T, 0, stream>>>(
      xb, nullptr, Wf1l, Wf1r, nullptr, p1, q1);

  // hidden = relu(l2norm(mean_agg(p1) + bl1 + q1))  -> bf16
  k_agg<H, true, true><<<2048, T, 0, stream>>>(p1, q1, bl1, deg, start, csr_src, hiddenb);

  // h = relu([x, hidden] @ Wlin + blin)  -> bf16
  k_mf<F, H, H, 4, 1, true, true, true><<<NT64, T, 0, stream>>>(
      xb, hiddenb, Wflin, nullptr, blin, hb, nullptr);

  // p2 = h@Wl2, q2 = h@Wr2  (MFMA, N=40 padded to 48)
  k_mf<H, 0, C, 3, 2, false, false, false><<<NT64, T, 0, stream>>>(
      hb, nullptr, Wf2l, Wf2r, nullptr, p2, q2);

  // out = l2norm(mean_agg(p2) + bl2 + q2)
  k_agg<C, false, false><<<2048, T, 0, stream>>>(p2, q2, bl2, deg, start, csr_src, out);
}

// Round 9
// 209.284 us; speedup vs baseline: 1.3930x; 1.1102x over previous
//
#include <hip/hip_runtime.h>

static constexpr int NN = 50000;   // nodes
static constexpr int NE = 800000;  // edges
static constexpr int F  = 128;     // input features
static constexpr int H  = 64;      // hidden
static constexpr int C  = 40;      // classes

static constexpr int NB_BK = 8;          // node buckets (XCD-aligned)
static constexpr int NCH   = 32;         // edge chunks
static constexpr int ECH   = NE / NCH;   // 25000 edges per chunk
static constexpr int NBK   = NN / NB_BK; // 6250 nodes per bucket
static constexpr int NCSR  = NB_BK * NCH; // 256 blocks for hist/fill
static constexpr int NT64  = (NN + 63) / 64;  // 782 node tiles

typedef __attribute__((ext_vector_type(8))) short bf16x8;
typedef __attribute__((ext_vector_type(4))) float f32x4;

__device__ inline unsigned short f2bf(float f) {
  unsigned int u = __builtin_bit_cast(unsigned int, f);
  u = (u + 0x7fff + ((u >> 16) & 1)) >> 16;  // RNE
  return (unsigned short)u;
}
__device__ inline float bf2f(unsigned short u) {
  return __builtin_bit_cast(float, (unsigned int)u << 16);
}

// ---------------- device bodies (fused via block-range partition) -----------

__device__ void hist_body(int bid, const int* __restrict__ ei,
                          int* __restrict__ hist, int* __restrict__ counter) {
  __shared__ int cnt[NBK];
  int i = bid & 7;
  int j = bid >> 3;
  for (int t = threadIdx.x; t < NBK; t += 256) cnt[t] = 0;
  __syncthreads();
  if (bid == 0 && threadIdx.x == 0) *counter = 0;  // consumed by next launch
  int lo = i * NBK;
  const int* dst = ei + NE + j * ECH;
  for (int base = threadIdx.x * 4; base < ECH; base += 256 * 4) {
    int4 d4 = *reinterpret_cast<const int4*>(dst + base);
    if ((unsigned)(d4.x - lo) < (unsigned)NBK) atomicAdd(&cnt[d4.x - lo], 1);
    if ((unsigned)(d4.y - lo) < (unsigned)NBK) atomicAdd(&cnt[d4.y - lo], 1);
    if ((unsigned)(d4.z - lo) < (unsigned)NBK) atomicAdd(&cnt[d4.z - lo], 1);
    if ((unsigned)(d4.w - lo) < (unsigned)NBK) atomicAdd(&cnt[d4.w - lo], 1);
  }
  __syncthreads();
  int* hrow = hist + (size_t)j * NN + lo;
  for (int t = threadIdx.x; t < NBK; t += 256) hrow[t] = cnt[t];
}

__device__ void cvt_body(int bid, const float* __restrict__ x,
                         unsigned short* __restrict__ xb) {
  int id = bid * 256 + threadIdx.x;
  int ns = NT64 * 256;
  for (int i = id; i < NN * F / 4; i += ns) {
    float4 v = reinterpret_cast<const float4*>(x)[i];
    ushort4 o = {f2bf(v.x), f2bf(v.y), f2bf(v.z), f2bf(v.w)};
    reinterpret_cast<ushort4*>(xb)[i] = o;
  }
}

__device__ void scan_body(int bid, int* __restrict__ hist,
                          int* __restrict__ deg, int* __restrict__ start,
                          int* __restrict__ counter) {
  int lane = threadIdx.x & 63;
  int wid  = (bid * 256 + threadIdx.x) >> 6;  // 0..783, nchunks=782
  int nchunks = (NN + 63) >> 6;
  if (wid >= nchunks) return;
  int n = (wid << 6) + lane;
  int d = 0;
  if (n < NN) {
    int run = 0;
#pragma unroll
    for (int j = 0; j < NCH; ++j) {
      int v = hist[(size_t)j * NN + n];
      hist[(size_t)j * NN + n] = run;
      run += v;
    }
    d = run;
  }
  int inc = d;
#pragma unroll
  for (int off = 1; off < 64; off <<= 1) {
    int t = __shfl_up(inc, off, 64);
    if (lane >= off) inc += t;
  }
  int total = __shfl(inc, 63, 64);
  int base = 0;
  if (lane == 63) base = atomicAdd(counter, total);
  base = __shfl(base, 63, 64);
  if (n < NN) {
    deg[n]   = d;
    start[n] = base + inc - d;
  }
}

// Wf[s][nt][lane][j] = bf16(W[s*32 + (lane>>4)*8 + j][nt*16 + (lane&15)])
__device__ inline void packW(const float* __restrict__ W, int J, int NT,
                             unsigned short* __restrict__ Wf, int idx) {
  int j  = idx & 7;
  int l  = (idx >> 3) & 63;
  int nt = (idx >> 9) % NT;
  int s  = idx / (512 * NT);
  int k  = s * 32 + (l >> 4) * 8 + j;
  int n  = nt * 16 + (l & 15);
  float v = (n < J) ? W[k * J + n] : 0.f;
  Wf[idx] = f2bf(v);
}

__device__ void prep_body(int bid,
                          const float* __restrict__ Wl1, const float* __restrict__ Wr1,
                          const float* __restrict__ Wlin,
                          const float* __restrict__ Wl2, const float* __restrict__ Wr2,
                          unsigned short* __restrict__ Wf1l, unsigned short* __restrict__ Wf1r,
                          unsigned short* __restrict__ Wflin,
                          unsigned short* __restrict__ Wf2l, unsigned short* __restrict__ Wf2r) {
  int id0 = bid * 256 + threadIdx.x;
  int ns  = 48 * 256;
  for (int i = id0; i < 4 * 4 * 512; i += ns) packW(Wl1, 64, 4, Wf1l, i);
  for (int i = id0; i < 4 * 4 * 512; i += ns) packW(Wr1, 64, 4, Wf1r, i);
  for (int i = id0; i < 6 * 4 * 512; i += ns) packW(Wlin, 64, 4, Wflin, i);
  for (int i = id0; i < 2 * 3 * 512; i += ns) packW(Wl2, 40, 3, Wf2l, i);
  for (int i = id0; i < 2 * 3 * 512; i += ns) packW(Wr2, 40, 3, Wf2r, i);
}

__device__ void fill2_body(int bid, const int* __restrict__ ei,
                           const int* __restrict__ hist,
                           const int* __restrict__ start,
                           int* __restrict__ csr_src) {
  __shared__ int fill[NBK];
  int i = bid & 7;
  int j = bid >> 3;
  int lo = i * NBK;
  const int* hrow = hist + (size_t)j * NN + lo;
  for (int t = threadIdx.x; t < NBK; t += 256) fill[t] = start[lo + t] + hrow[t];
  __syncthreads();
  const int* srcp = ei + j * ECH;
  const int* dstp = ei + NE + j * ECH;
  for (int base = threadIdx.x * 4; base < ECH; base += 256 * 4) {
    int4 s4 = *reinterpret_cast<const int4*>(srcp + base);
    int4 d4 = *reinterpret_cast<const int4*>(dstp + base);
    if ((unsigned)(d4.x - lo) < (unsigned)NBK) { int p = atomicAdd(&fill[d4.x - lo], 1); csr_src[p] = s4.x; }
    if ((unsigned)(d4.y - lo) < (unsigned)NBK) { int p = atomicAdd(&fill[d4.y - lo], 1); csr_src[p] = s4.y; }
    if ((unsigned)(d4.z - lo) < (unsigned)NBK) { int p = atomicAdd(&fill[d4.z - lo], 1); csr_src[p] = s4.z; }
    if ((unsigned)(d4.w - lo) < (unsigned)NBK) { int p = atomicAdd(&fill[d4.w - lo], 1); csr_src[p] = s4.w; }
  }
}

// ---------------- dense GEMM via MFMA bf16 (m89-verified C/D mapping) -------

template <int K1, int K2, int JOUT, int NT, int NMAT, bool BIAS, bool RELU, bool OUTBF>
__device__ void mf_body(int bid,
                        const unsigned short* __restrict__ A1,
                        const unsigned short* __restrict__ A2,
                        const unsigned short* __restrict__ Wf0,
                        const unsigned short* __restrict__ Wf1,
                        const float* __restrict__ bias,
                        void* __restrict__ Y0v, void* __restrict__ Y1v) {
  constexpr int K   = K1 + K2;
  constexpr int NKS = K / 32;
  int lane = threadIdx.x & 63;
  int w    = __builtin_amdgcn_readfirstlane(threadIdx.x >> 6);
  int m    = lane & 15;
  int kg   = lane >> 4;
  int n0   = bid * 64;
  int row  = n0 + w * 16 + m;
  int rowc = row < NN ? row : NN - 1;

  f32x4 acc[NMAT][NT];
#pragma unroll
  for (int mt = 0; mt < NMAT; ++mt)
#pragma unroll
    for (int nt = 0; nt < NT; ++nt) acc[mt][nt] = {0.f, 0.f, 0.f, 0.f};

#pragma unroll
  for (int s = 0; s < NKS; ++s) {
    const unsigned short* Ab; int rs, koff;
    if (s * 32 < K1) { Ab = A1; rs = K1; koff = s * 32; }
    else             { Ab = A2; rs = K2; koff = s * 32 - K1; }
    bf16x8 a = *reinterpret_cast<const bf16x8*>(Ab + (size_t)rowc * rs + koff + kg * 8);
#pragma unroll
    for (int mt = 0; mt < NMAT; ++mt) {
      const unsigned short* Wf = (NMAT == 2 && mt) ? Wf1 : Wf0;
#pragma unroll
      for (int nt = 0; nt < NT; ++nt) {
        bf16x8 b = *reinterpret_cast<const bf16x8*>(Wf + (size_t)((s * NT + nt) * 64 + lane) * 8);
        acc[mt][nt] = __builtin_amdgcn_mfma_f32_16x16x32_bf16(a, b, acc[mt][nt], 0, 0, 0);
      }
    }
  }

#pragma unroll
  for (int mt = 0; mt < NMAT; ++mt) {
    void* Yv = (NMAT == 2 && mt) ? Y1v : Y0v;
#pragma unroll
    for (int nt = 0; nt < NT; ++nt) {
      int gc = nt * 16 + m;
      bool cv = gc < JOUT;
      float bb = (BIAS && cv) ? bias[gc] : 0.f;
#pragma unroll
      for (int r = 0; r < 4; ++r) {
        int grow = n0 + w * 16 + kg * 4 + r;
        if (grow < NN && cv) {
          float v = acc[mt][nt][r] + bb;
          if (RELU) v = fmaxf(v, 0.f);
          if (OUTBF) ((unsigned short*)Yv)[(size_t)grow * JOUT + gc] = f2bf(v);
          else       ((float*)Yv)[(size_t)grow * JOUT + gc] = v;
        }
      }
    }
  }
}

// ---------------- fused kernels ---------------------------------------------

__global__ __launch_bounds__(256) void k_p1(const int* __restrict__ ei,
                                            int* __restrict__ hist,
                                            int* __restrict__ counter,
                                            const float* __restrict__ x,
                                            unsigned short* __restrict__ xb) {
  if (blockIdx.x < NCSR) hist_body(blockIdx.x, ei, hist, counter);
  else                   cvt_body(blockIdx.x - NCSR, x, xb);
}

__global__ __launch_bounds__(256) void k_p2(int* __restrict__ hist,
                                            int* __restrict__ deg,
                                            int* __restrict__ start,
                                            int* __restrict__ counter,
                                            const float* Wl1, const float* Wr1,
                                            const float* Wlin,
                                            const float* Wl2, const float* Wr2,
                                            unsigned short* Wf1l, unsigned short* Wf1r,
                                            unsigned short* Wflin,
                                            unsigned short* Wf2l, unsigned short* Wf2r) {
  if (blockIdx.x < 196) scan_body(blockIdx.x, hist, deg, start, counter);
  else prep_body(blockIdx.x - 196, Wl1, Wr1, Wlin, Wl2, Wr2,
                 Wf1l, Wf1r, Wflin, Wf2l, Wf2r);
}

__global__ __launch_bounds__(256) void k_p3(const int* __restrict__ ei,
                                            const int* __restrict__ hist,
                                            const int* __restrict__ start,
                                            int* __restrict__ csr_src,
                                            const unsigned short* __restrict__ xb,
                                            const unsigned short* __restrict__ Wf1l,
                                            const unsigned short* __restrict__ Wf1r,
                                            unsigned short* __restrict__ p1b,
                                            unsigned short* __restrict__ q1b) {
  if (blockIdx.x < NCSR) fill2_body(blockIdx.x, ei, hist, start, csr_src);
  else mf_body<F, 0, H, 4, 2, false, false, true>(blockIdx.x - NCSR, xb, nullptr,
                                                  Wf1l, Wf1r, nullptr, p1b, q1b);
}

template <int K1, int K2, int JOUT, int NT, int NMAT, bool BIAS, bool RELU, bool OUTBF>
__global__ __launch_bounds__(256) void k_mf(const unsigned short* __restrict__ A1,
                                            const unsigned short* __restrict__ A2,
                                            const unsigned short* __restrict__ Wf0,
                                            const unsigned short* __restrict__ Wf1,
                                            const float* __restrict__ bias,
                                            void* __restrict__ Y0v,
                                            void* __restrict__ Y1v) {
  mf_body<K1, K2, JOUT, NT, NMAT, BIAS, RELU, OUTBF>(blockIdx.x, A1, A2, Wf0, Wf1,
                                                     bias, Y0v, Y1v);
}

// ---------------- aggregation: scalar CSR fetch + 16-deep bf16 gather -------

template <int JC, bool RELU, bool OUTBF>
__global__ __launch_bounds__(256) void k_agg(const unsigned short* __restrict__ p,
                                             const unsigned short* __restrict__ q,
                                             const float* __restrict__ bl,
                                             const int* __restrict__ deg,
                                             const int* __restrict__ start,
                                             const int* __restrict__ csr_src,
                                             void* __restrict__ outp) {
  int lane = threadIdx.x & 63;
  int wid  = (blockIdx.x * blockDim.x + threadIdx.x) >> 6;
  int nw   = (gridDim.x * blockDim.x) >> 6;
  bool jl = lane < JC;
  int lidx = jl ? lane : 0;
  for (int node = wid; node < NN; node += nw) {
    int d  = __builtin_amdgcn_readfirstlane(deg[node]);
    int st = __builtin_amdgcn_readfirstlane(start[node]);
    float acc8[8];
#pragma unroll
    for (int i = 0; i < 8; ++i) acc8[i] = 0.f;
    int t = 0;
    for (; t + 16 <= d; t += 16) {
      int s[16];
#pragma unroll
      for (int i = 0; i < 16; ++i)
        s[i] = __builtin_amdgcn_readfirstlane(csr_src[st + t + i]);
      unsigned short v[16];
#pragma unroll
      for (int i = 0; i < 16; ++i) v[i] = p[(size_t)s[i] * JC + lidx];
#pragma unroll
      for (int i = 0; i < 16; ++i) acc8[i & 7] += bf2f(v[i]);
    }
    for (; t + 4 <= d; t += 4) {
      int s0 = __builtin_amdgcn_readfirstlane(csr_src[st + t + 0]);
      int s1 = __builtin_amdgcn_readfirstlane(csr_src[st + t + 1]);
      int s2 = __builtin_amdgcn_readfirstlane(csr_src[st + t + 2]);
      int s3 = __builtin_amdgcn_readfirstlane(csr_src[st + t + 3]);
      unsigned short v0 = p[(size_t)s0 * JC + lidx];
      unsigned short v1 = p[(size_t)s1 * JC + lidx];
      unsigned short v2 = p[(size_t)s2 * JC + lidx];
      unsigned short v3 = p[(size_t)s3 * JC + lidx];
      acc8[0] += bf2f(v0); acc8[1] += bf2f(v1);
      acc8[2] += bf2f(v2); acc8[3] += bf2f(v3);
    }
    for (; t < d; ++t) {
      int s = __builtin_amdgcn_readfirstlane(csr_src[st + t]);
      acc8[0] += bf2f(p[(size_t)s * JC + lidx]);
    }
    float acc = ((acc8[0] + acc8[1]) + (acc8[2] + acc8[3])) +
                ((acc8[4] + acc8[5]) + (acc8[6] + acc8[7]));
    float mean = acc / fmaxf((float)d, 1.0f);
    float v = 0.f;
    if (jl) v = mean + bl[lidx] + bf2f(q[(size_t)node * JC + lidx]);
    float ss = v * v;
#pragma unroll
    for (int off = 32; off > 0; off >>= 1) ss += __shfl_xor(ss, off, 64);
    v = v / fmaxf(sqrtf(ss), 1e-12f);
    if (RELU) v = fmaxf(v, 0.f);
    if (jl) {
      if (OUTBF) ((unsigned short*)outp)[(size_t)node * JC + lidx] = f2bf(v);
      else       ((float*)outp)[(size_t)node * JC + lidx] = v;
    }
  }
}

// ---------------- launch ----------------------------------------------------

static inline size_t align256(size_t x) { return (x + 255) & ~(size_t)255; }

extern "C" void kernel_launch(void* const* d_in, const int* in_sizes, int n_in,
                              void* d_out, int out_size, void* d_ws, size_t ws_size,
                              hipStream_t stream) {
  const float* x    = (const float*)d_in[0];
  const int*   ei   = (const int*)d_in[1];
  const float* Wl1  = (const float*)d_in[2];
  const float* bl1  = (const float*)d_in[3];
  const float* Wr1  = (const float*)d_in[4];
  const float* Wlin = (const float*)d_in[5];
  const float* blin = (const float*)d_in[6];
  const float* Wl2  = (const float*)d_in[7];
  const float* bl2  = (const float*)d_in[8];
  const float* Wr2  = (const float*)d_in[9];
  float* out = (float*)d_out;

  char* w = (char*)d_ws;
  size_t off = 0;
  int* deg     = (int*)(w + off); off += align256((size_t)NN * 4);
  int* start   = (int*)(w + off); off += align256((size_t)NN * 4);
  int* counter = (int*)(w + off); off += 256;
  int* csr_src = (int*)(w + off); off += align256((size_t)NE * 4);
  int* hist    = (int*)(w + off); off += align256((size_t)NCH * NN * 4);  // 6.4 MB
  unsigned short* xb      = (unsigned short*)(w + off); off += align256((size_t)NN * F * 2);
  unsigned short* hiddenb = (unsigned short*)(w + off); off += align256((size_t)NN * H * 2);
  unsigned short* hb      = (unsigned short*)(w + off); off += align256((size_t)NN * H * 2);
  unsigned short* p1b = (unsigned short*)(w + off); off += align256((size_t)NN * H * 2);
  unsigned short* q1b = (unsigned short*)(w + off); off += align256((size_t)NN * H * 2);
  unsigned short* p2b = (unsigned short*)(w + off); off += align256((size_t)NN * C * 2);
  unsigned short* q2b = (unsigned short*)(w + off); off += align256((size_t)NN * C * 2);
  unsigned short* Wf1l  = (unsigned short*)(w + off); off += align256(4 * 4 * 512 * 2);
  unsigned short* Wf1r  = (unsigned short*)(w + off); off += align256(4 * 4 * 512 * 2);
  unsigned short* Wflin = (unsigned short*)(w + off); off += align256(6 * 4 * 512 * 2);
  unsigned short* Wf2l  = (unsigned short*)(w + off); off += align256(2 * 3 * 512 * 2);
  unsigned short* Wf2r  = (unsigned short*)(w + off); off += align256(2 * 3 * 512 * 2);

  const int T = 256;

  // 1: dst histogram (256 blk) || x->bf16 (782 blk); zeroes counter
  k_p1<<<NCSR + NT64, T, 0, stream>>>(ei, hist, counter, x, xb);
  // 2: hist scan -> deg/start (196 blk) || weight fragment pack (48 blk)
  k_p2<<<244, T, 0, stream>>>(hist, deg, start, counter,
                              Wl1, Wr1, Wlin, Wl2, Wr2,
                              Wf1l, Wf1r, Wflin, Wf2l, Wf2r);
  // 3: CSR fill (256 blk) || p1=x@Wl1, q1=x@Wr1 MFMA (782 blk)
  k_p3<<<NCSR + NT64, T, 0, stream>>>(ei, hist, start, csr_src,
                                      xb, Wf1l, Wf1r, p1b, q1b);
  // 4: hidden = relu(l2norm(mean_agg(p1) + bl1 + q1)) -> bf16
  k_agg<H, true, true><<<2048, T, 0, stream>>>(p1b, q1b, bl1, deg, start, csr_src, hiddenb);
  // 5: h = relu([x, hidden] @ Wlin + blin) -> bf16
  k_mf<F, H, H, 4, 1, true, true, true><<<NT64, T, 0, stream>>>(
      xb, hiddenb, Wflin, nullptr, blin, hb, nullptr);
  // 6: p2 = h@Wl2, q2 = h@Wr2 -> bf16
  k_mf<H, 0, C, 3, 2, false, false, true><<<NT64, T, 0, stream>>>(
      hb, nullptr, Wf2l, Wf2r, nullptr, p2b, q2b);
  // 7: out = l2norm(mean_agg(p2) + bl2 + q2)
  k_agg<C, false, false><<<2048, T, 0, stream>>>(p2b, q2b, bl2, deg, start, csr_src, out);
}

// Round 10
// 204.690 us; speedup vs baseline: 1.4243x; 1.0224x over previous
//
#include <hip/hip_runtime.h>

static constexpr int NN = 50000;   // nodes
static constexpr int NE = 800000;  // edges
static constexpr int F  = 128;     // input features
static constexpr int H  = 64;      // hidden
static constexpr int C  = 40;      // classes

static constexpr int NB_BK = 8;          // node buckets (XCD-aligned)
static constexpr int NCH   = 32;         // edge chunks
static constexpr int ECH   = NE / NCH;   // 25000 edges per chunk
static constexpr int NBK   = NN / NB_BK; // 6250 nodes per bucket
static constexpr int NCSR  = NB_BK * NCH; // 256 blocks for hist/fill
static constexpr int NT64  = (NN + 63) / 64;  // 782 node tiles

typedef __attribute__((ext_vector_type(8))) short bf16x8;
typedef __attribute__((ext_vector_type(8))) unsigned short u16x8;
typedef __attribute__((ext_vector_type(4))) float f32x4;

__device__ inline unsigned short f2bf(float f) {
  unsigned int u = __builtin_bit_cast(unsigned int, f);
  u = (u + 0x7fff + ((u >> 16) & 1)) >> 16;  // RNE
  return (unsigned short)u;
}
__device__ inline float bf2f(unsigned short u) {
  return __builtin_bit_cast(float, (unsigned int)u << 16);
}

// ---------------- device bodies (fused via block-range partition) -----------

__device__ void hist_body(int bid, const int* __restrict__ ei,
                          int* __restrict__ hist, int* __restrict__ counter) {
  __shared__ int cnt[NBK];
  int i = bid & 7;
  int j = bid >> 3;
  for (int t = threadIdx.x; t < NBK; t += 256) cnt[t] = 0;
  __syncthreads();
  if (bid == 0 && threadIdx.x == 0) *counter = 0;  // consumed by next launch
  int lo = i * NBK;
  const int* dst = ei + NE + j * ECH;
  for (int base = threadIdx.x * 4; base < ECH; base += 256 * 4) {
    int4 d4 = *reinterpret_cast<const int4*>(dst + base);
    if ((unsigned)(d4.x - lo) < (unsigned)NBK) atomicAdd(&cnt[d4.x - lo], 1);
    if ((unsigned)(d4.y - lo) < (unsigned)NBK) atomicAdd(&cnt[d4.y - lo], 1);
    if ((unsigned)(d4.z - lo) < (unsigned)NBK) atomicAdd(&cnt[d4.z - lo], 1);
    if ((unsigned)(d4.w - lo) < (unsigned)NBK) atomicAdd(&cnt[d4.w - lo], 1);
  }
  __syncthreads();
  int* hrow = hist + (size_t)j * NN + lo;
  for (int t = threadIdx.x; t < NBK; t += 256) hrow[t] = cnt[t];
}

__device__ void cvt_body(int bid, const float* __restrict__ x,
                         unsigned short* __restrict__ xb) {
  int id = bid * 256 + threadIdx.x;
  int ns = NT64 * 256;
  for (int i = id; i < NN * F / 4; i += ns) {
    float4 v = reinterpret_cast<const float4*>(x)[i];
    ushort4 o = {f2bf(v.x), f2bf(v.y), f2bf(v.z), f2bf(v.w)};
    reinterpret_cast<ushort4*>(xb)[i] = o;
  }
}

__device__ void scan_body(int bid, int* __restrict__ hist,
                          int* __restrict__ deg, int* __restrict__ start,
                          int* __restrict__ counter) {
  int lane = threadIdx.x & 63;
  int wid  = (bid * 256 + threadIdx.x) >> 6;
  int nchunks = (NN + 63) >> 6;
  if (wid >= nchunks) return;
  int n = (wid << 6) + lane;
  int d = 0;
  if (n < NN) {
    int run = 0;
#pragma unroll
    for (int j = 0; j < NCH; ++j) {
      int v = hist[(size_t)j * NN + n];
      hist[(size_t)j * NN + n] = run;
      run += v;
    }
    d = run;
  }
  int inc = d;
#pragma unroll
  for (int off = 1; off < 64; off <<= 1) {
    int t = __shfl_up(inc, off, 64);
    if (lane >= off) inc += t;
  }
  int total = __shfl(inc, 63, 64);
  int base = 0;
  if (lane == 63) base = atomicAdd(counter, total);
  base = __shfl(base, 63, 64);
  if (n < NN) {
    deg[n]   = d;
    start[n] = base + inc - d;
  }
}

// Wf[s][nt][lane][j] = bf16(W[s*32 + (lane>>4)*8 + j][nt*16 + (lane&15)]), 0-pad n>=J
__device__ inline void packW(const float* __restrict__ W, int J, int NT,
                             unsigned short* __restrict__ Wf, int idx) {
  int j  = idx & 7;
  int l  = (idx >> 3) & 63;
  int nt = (idx >> 9) % NT;
  int s  = idx / (512 * NT);
  int k  = s * 32 + (l >> 4) * 8 + j;
  int n  = nt * 16 + (l & 15);
  float v = (n < J) ? W[k * J + n] : 0.f;
  Wf[idx] = f2bf(v);
}

__device__ void prep_body(int bid,
                          const float* __restrict__ Wl1, const float* __restrict__ Wr1,
                          const float* __restrict__ Wlin,
                          const float* __restrict__ Wl2, const float* __restrict__ Wr2,
                          unsigned short* __restrict__ Wf1l, unsigned short* __restrict__ Wf1r,
                          unsigned short* __restrict__ Wflin,
                          unsigned short* __restrict__ Wf2l, unsigned short* __restrict__ Wf2r) {
  int id0 = bid * 256 + threadIdx.x;
  int ns  = 48 * 256;
  for (int i = id0; i < 4 * 4 * 512; i += ns) packW(Wl1, 64, 4, Wf1l, i);
  for (int i = id0; i < 4 * 4 * 512; i += ns) packW(Wr1, 64, 4, Wf1r, i);
  for (int i = id0; i < 6 * 4 * 512; i += ns) packW(Wlin, 64, 4, Wflin, i);
  for (int i = id0; i < 2 * 4 * 512; i += ns) packW(Wl2, 40, 4, Wf2l, i);  // pad cols 40..63 = 0
  for (int i = id0; i < 2 * 4 * 512; i += ns) packW(Wr2, 40, 4, Wf2r, i);
}

__device__ void fill2_body(int bid, const int* __restrict__ ei,
                           const int* __restrict__ hist,
                           const int* __restrict__ start,
                           int* __restrict__ csr_src) {
  __shared__ int fill[NBK];
  int i = bid & 7;
  int j = bid >> 3;
  int lo = i * NBK;
  const int* hrow = hist + (size_t)j * NN + lo;
  for (int t = threadIdx.x; t < NBK; t += 256) fill[t] = start[lo + t] + hrow[t];
  __syncthreads();
  const int* srcp = ei + j * ECH;
  const int* dstp = ei + NE + j * ECH;
  for (int base = threadIdx.x * 4; base < ECH; base += 256 * 4) {
    int4 s4 = *reinterpret_cast<const int4*>(srcp + base);
    int4 d4 = *reinterpret_cast<const int4*>(dstp + base);
    if ((unsigned)(d4.x - lo) < (unsigned)NBK) { int p = atomicAdd(&fill[d4.x - lo], 1); csr_src[p] = s4.x; }
    if ((unsigned)(d4.y - lo) < (unsigned)NBK) { int p = atomicAdd(&fill[d4.y - lo], 1); csr_src[p] = s4.y; }
    if ((unsigned)(d4.z - lo) < (unsigned)NBK) { int p = atomicAdd(&fill[d4.z - lo], 1); csr_src[p] = s4.z; }
    if ((unsigned)(d4.w - lo) < (unsigned)NBK) { int p = atomicAdd(&fill[d4.w - lo], 1); csr_src[p] = s4.w; }
  }
}

// ---------------- dense GEMM via MFMA bf16 (m89-verified C/D mapping) -------

template <int K1, int K2, int JOUT, int NT, int NMAT, bool BIAS, bool RELU, bool OUTBF>
__device__ void mf_body(int bid,
                        const unsigned short* __restrict__ A1,
                        const unsigned short* __restrict__ A2,
                        const unsigned short* __restrict__ Wf0,
                        const unsigned short* __restrict__ Wf1,
                        const float* __restrict__ bias,
                        void* __restrict__ Y0v, void* __restrict__ Y1v) {
  constexpr int K   = K1 + K2;
  constexpr int NKS = K / 32;
  int lane = threadIdx.x & 63;
  int w    = __builtin_amdgcn_readfirstlane(threadIdx.x >> 6);
  int m    = lane & 15;
  int kg   = lane >> 4;
  int n0   = bid * 64;
  int row  = n0 + w * 16 + m;
  int rowc = row < NN ? row : NN - 1;

  f32x4 acc[NMAT][NT];
#pragma unroll
  for (int mt = 0; mt < NMAT; ++mt)
#pragma unroll
    for (int nt = 0; nt < NT; ++nt) acc[mt][nt] = {0.f, 0.f, 0.f, 0.f};

#pragma unroll
  for (int s = 0; s < NKS; ++s) {
    const unsigned short* Ab; int rs, koff;
    if (s * 32 < K1) { Ab = A1; rs = K1; koff = s * 32; }
    else             { Ab = A2; rs = K2; koff = s * 32 - K1; }
    bf16x8 a = *reinterpret_cast<const bf16x8*>(Ab + (size_t)rowc * rs + koff + kg * 8);
#pragma unroll
    for (int mt = 0; mt < NMAT; ++mt) {
      const unsigned short* Wf = (NMAT == 2 && mt) ? Wf1 : Wf0;
#pragma unroll
      for (int nt = 0; nt < NT; ++nt) {
        bf16x8 b = *reinterpret_cast<const bf16x8*>(Wf + (size_t)((s * NT + nt) * 64 + lane) * 8);
        acc[mt][nt] = __builtin_amdgcn_mfma_f32_16x16x32_bf16(a, b, acc[mt][nt], 0, 0, 0);
      }
    }
  }

#pragma unroll
  for (int mt = 0; mt < NMAT; ++mt) {
    void* Yv = (NMAT == 2 && mt) ? Y1v : Y0v;
#pragma unroll
    for (int nt = 0; nt < NT; ++nt) {
      int gc = nt * 16 + m;
      bool cv = gc < JOUT;
      float bb = (BIAS && cv) ? bias[gc] : 0.f;
#pragma unroll
      for (int r = 0; r < 4; ++r) {
        int grow = n0 + w * 16 + kg * 4 + r;
        if (grow < NN && cv) {
          float v = acc[mt][nt][r] + bb;
          if (RELU) v = fmaxf(v, 0.f);
          if (OUTBF) ((unsigned short*)Yv)[(size_t)grow * JOUT + gc] = f2bf(v);
          else       ((float*)Yv)[(size_t)grow * JOUT + gc] = v;
        }
      }
    }
  }
}

// ---------------- fused kernels ---------------------------------------------

__global__ __launch_bounds__(256) void k_p1(const int* __restrict__ ei,
                                            int* __restrict__ hist,
                                            int* __restrict__ counter,
                                            const float* __restrict__ x,
                                            unsigned short* __restrict__ xb) {
  if (blockIdx.x < NCSR) hist_body(blockIdx.x, ei, hist, counter);
  else                   cvt_body(blockIdx.x - NCSR, x, xb);
}

__global__ __launch_bounds__(256) void k_p2(int* __restrict__ hist,
                                            int* __restrict__ deg,
                                            int* __restrict__ start,
                                            int* __restrict__ counter,
                                            const float* Wl1, const float* Wr1,
                                            const float* Wlin,
                                            const float* Wl2, const float* Wr2,
                                            unsigned short* Wf1l, unsigned short* Wf1r,
                                            unsigned short* Wflin,
                                            unsigned short* Wf2l, unsigned short* Wf2r) {
  if (blockIdx.x < 196) scan_body(blockIdx.x, hist, deg, start, counter);
  else prep_body(blockIdx.x - 196, Wl1, Wr1, Wlin, Wl2, Wr2,
                 Wf1l, Wf1r, Wflin, Wf2l, Wf2r);
}

__global__ __launch_bounds__(256) void k_p3(const int* __restrict__ ei,
                                            const int* __restrict__ hist,
                                            const int* __restrict__ start,
                                            int* __restrict__ csr_src,
                                            const unsigned short* __restrict__ xb,
                                            const unsigned short* __restrict__ Wf1l,
                                            const unsigned short* __restrict__ Wf1r,
                                            unsigned short* __restrict__ p1b,
                                            unsigned short* __restrict__ q1b) {
  if (blockIdx.x < NCSR) fill2_body(blockIdx.x, ei, hist, start, csr_src);
  else mf_body<F, 0, H, 4, 2, false, false, true>(blockIdx.x - NCSR, xb, nullptr,
                                                  Wf1l, Wf1r, nullptr, p1b, q1b);
}

template <int K1, int K2, int JOUT, int NT, int NMAT, bool BIAS, bool RELU, bool OUTBF>
__global__ __launch_bounds__(256) void k_mf(const unsigned short* __restrict__ A1,
                                            const unsigned short* __restrict__ A2,
                                            const unsigned short* __restrict__ Wf0,
                                            const unsigned short* __restrict__ Wf1,
                                            const float* __restrict__ bias,
                                            void* __restrict__ Y0v,
                                            void* __restrict__ Y1v) {
  mf_body<K1, K2, JOUT, NT, NMAT, BIAS, RELU, OUTBF>(blockIdx.x, A1, A2, Wf0, Wf1,
                                                     bias, Y0v, Y1v);
}

// ---------------- aggregation: lane = (edge e, chunk c); 1KB per gather -----
// Wave = 8 edges x 8 feature-chunks. One global_load_dwordx4 per lane moves
// 8 full edge rows; edge ids are per-lane vector loads (single waitcnt
// domain, no SMEM in loop). Row stride fixed at 64 bf16 (conv2 zero-padded).

template <int JCR, bool RELU, bool OUTBF>
__global__ __launch_bounds__(256) void k_aggv(const unsigned short* __restrict__ p,
                                              const unsigned short* __restrict__ q,
                                              const float* __restrict__ bl,
                                              const int* __restrict__ deg,
                                              const int* __restrict__ start,
                                              const int* __restrict__ csr_src,
                                              void* __restrict__ outp) {
  constexpr int ST = 64;  // padded row stride (bf16)
  int lane = threadIdx.x & 63;
  int e = lane >> 3, c = lane & 7;
  int wid = (blockIdx.x * blockDim.x + threadIdx.x) >> 6;
  int nw  = (gridDim.x * blockDim.x) >> 6;

  float blv[8];
#pragma unroll
  for (int j = 0; j < 8; ++j) {
    int f = c * 8 + j;
    blv[j] = (f < JCR) ? bl[f] : 0.f;
  }

  for (int node = wid; node < NN; node += nw) {
    int d  = __builtin_amdgcn_readfirstlane(deg[node]);
    int st = __builtin_amdgcn_readfirstlane(start[node]);
    float a0[8], a1[8];
#pragma unroll
    for (int j = 0; j < 8; ++j) { a0[j] = 0.f; a1[j] = 0.f; }
    int r = 0;
    for (; r + 16 <= d; r += 16) {
      int i0 = csr_src[st + r + e];
      int i1 = csr_src[st + r + 8 + e];
      u16x8 v0 = *reinterpret_cast<const u16x8*>(p + (size_t)i0 * ST + c * 8);
      u16x8 v1 = *reinterpret_cast<const u16x8*>(p + (size_t)i1 * ST + c * 8);
#pragma unroll
      for (int j = 0; j < 8; ++j) { a0[j] += bf2f(v0[j]); a1[j] += bf2f(v1[j]); }
    }
    if (r + 8 <= d) {
      int i0 = csr_src[st + r + e];
      u16x8 v0 = *reinterpret_cast<const u16x8*>(p + (size_t)i0 * ST + c * 8);
#pragma unroll
      for (int j = 0; j < 8; ++j) a0[j] += bf2f(v0[j]);
      r += 8;
    }
    int rem = d - r;
    if (rem > 0) {
      int ec = e < rem ? e : rem - 1;
      int i0 = csr_src[st + r + ec];
      u16x8 v0 = *reinterpret_cast<const u16x8*>(p + (size_t)i0 * ST + c * 8);
      if (e < rem) {
#pragma unroll
        for (int j = 0; j < 8; ++j) a0[j] += bf2f(v0[j]);
      }
    }
#pragma unroll
    for (int j = 0; j < 8; ++j) a0[j] += a1[j];
    // reduce over edge slots (lane bits 3..5)
#pragma unroll
    for (int ms = 8; ms <= 32; ms <<= 1)
#pragma unroll
      for (int j = 0; j < 8; ++j) a0[j] += __shfl_xor(a0[j], ms, 64);

    float inv = 1.f / fmaxf((float)d, 1.f);
    u16x8 qv = *reinterpret_cast<const u16x8*>(q + (size_t)node * ST + c * 8);
    float v[8];
    float ss = 0.f;
#pragma unroll
    for (int j = 0; j < 8; ++j) {
      int f = c * 8 + j;
      float t = a0[j] * inv + blv[j] + bf2f(qv[j]);
      if (f >= JCR) t = 0.f;  // padded cols are exact zeros anyway
      v[j] = t;
      ss += t * t;
    }
    // total sum-of-squares: reduce over chunks (lane bits 0..2)
#pragma unroll
    for (int ms = 1; ms <= 4; ms <<= 1) ss += __shfl_xor(ss, ms, 64);
    float rn = 1.f / fmaxf(sqrtf(ss), 1e-12f);

    if (e == 0 && c * 8 < JCR) {
      if (OUTBF) {
        u16x8 o;
#pragma unroll
        for (int j = 0; j < 8; ++j) {
          float t = v[j] * rn;
          if (RELU) t = fmaxf(t, 0.f);
          o[j] = f2bf(t);
        }
        *reinterpret_cast<u16x8*>((unsigned short*)outp + (size_t)node * JCR + c * 8) = o;
      } else {
        float* op = (float*)outp + (size_t)node * JCR + c * 8;
#pragma unroll
        for (int j = 0; j < 8; j += 4) {
          float4 o = {v[j] * rn, v[j + 1] * rn, v[j + 2] * rn, v[j + 3] * rn};
          if (RELU) {
            o.x = fmaxf(o.x, 0.f); o.y = fmaxf(o.y, 0.f);
            o.z = fmaxf(o.z, 0.f); o.w = fmaxf(o.w, 0.f);
          }
          *reinterpret_cast<float4*>(op + j) = o;
        }
      }
    }
  }
}

// ---------------- launch ----------------------------------------------------

static inline size_t align256(size_t x) { return (x + 255) & ~(size_t)255; }

extern "C" void kernel_launch(void* const* d_in, const int* in_sizes, int n_in,
                              void* d_out, int out_size, void* d_ws, size_t ws_size,
                              hipStream_t stream) {
  const float* x    = (const float*)d_in[0];
  const int*   ei   = (const int*)d_in[1];
  const float* Wl1  = (const float*)d_in[2];
  const float* bl1  = (const float*)d_in[3];
  const float* Wr1  = (const float*)d_in[4];
  const float* Wlin = (const float*)d_in[5];
  const float* blin = (const float*)d_in[6];
  const float* Wl2  = (const float*)d_in[7];
  const float* bl2  = (const float*)d_in[8];
  const float* Wr2  = (const float*)d_in[9];
  float* out = (float*)d_out;

  char* w = (char*)d_ws;
  size_t off = 0;
  int* deg     = (int*)(w + off); off += align256((size_t)NN * 4);
  int* start   = (int*)(w + off); off += align256((size_t)NN * 4);
  int* counter = (int*)(w + off); off += 256;
  int* csr_src = (int*)(w + off); off += align256((size_t)NE * 4);
  int* hist    = (int*)(w + off); off += align256((size_t)NCH * NN * 4);  // 6.4 MB
  unsigned short* xb      = (unsigned short*)(w + off); off += align256((size_t)NN * F * 2);
  unsigned short* hiddenb = (unsigned short*)(w + off); off += align256((size_t)NN * H * 2);
  unsigned short* hb      = (unsigned short*)(w + off); off += align256((size_t)NN * H * 2);
  unsigned short* p1b = (unsigned short*)(w + off); off += align256((size_t)NN * 64 * 2);
  unsigned short* q1b = (unsigned short*)(w + off); off += align256((size_t)NN * 64 * 2);
  unsigned short* p2b = (unsigned short*)(w + off); off += align256((size_t)NN * 64 * 2);
  unsigned short* q2b = (unsigned short*)(w + off); off += align256((size_t)NN * 64 * 2);
  unsigned short* Wf1l  = (unsigned short*)(w + off); off += align256(4 * 4 * 512 * 2);
  unsigned short* Wf1r  = (unsigned short*)(w + off); off += align256(4 * 4 * 512 * 2);
  unsigned short* Wflin = (unsigned short*)(w + off); off += align256(6 * 4 * 512 * 2);
  unsigned short* Wf2l  = (unsigned short*)(w + off); off += align256(2 * 4 * 512 * 2);
  unsigned short* Wf2r  = (unsigned short*)(w + off); off += align256(2 * 4 * 512 * 2);

  const int T = 256;

  // 1: dst histogram (256 blk) || x->bf16 (782 blk); zeroes counter
  k_p1<<<NCSR + NT64, T, 0, stream>>>(ei, hist, counter, x, xb);
  // 2: hist scan -> deg/start (196 blk) || weight fragment pack (48 blk)
  k_p2<<<244, T, 0, stream>>>(hist, deg, start, counter,
                              Wl1, Wr1, Wlin, Wl2, Wr2,
                              Wf1l, Wf1r, Wflin, Wf2l, Wf2r);
  // 3: CSR fill (256 blk) || p1=x@Wl1, q1=x@Wr1 MFMA (782 blk)
  k_p3<<<NCSR + NT64, T, 0, stream>>>(ei, hist, start, csr_src,
                                      xb, Wf1l, Wf1r, p1b, q1b);
  // 4: hidden = relu(l2norm(mean_agg(p1) + bl1 + q1)) -> bf16
  k_aggv<H, true, true><<<2048, T, 0, stream>>>(p1b, q1b, bl1, deg, start, csr_src, hiddenb);
  // 5: h = relu([x, hidden] @ Wlin + blin) -> bf16
  k_mf<F, H, H, 4, 1, true, true, true><<<NT64, T, 0, stream>>>(
      xb, hiddenb, Wflin, nullptr, blin, hb, nullptr);
  // 6: p2 = h@Wl2, q2 = h@Wr2 -> bf16, rows zero-padded to 64
  k_mf<H, 0, 64, 4, 2, false, false, true><<<NT64, T, 0, stream>>>(
      hb, nullptr, Wf2l, Wf2r, nullptr, p2b, q2b);
  // 7: out = l2norm(mean_agg(p2) + bl2 + q2)
  k_aggv<C, false, false><<<2048, T, 0, stream>>>(p2b, q2b, bl2, deg, start, csr_src, out);
}